// Round 8
// baseline (230.156 us; speedup 1.0000x reference)
//
#include <hip/hip_runtime.h>
#include <math.h>

#define TOK 16384
#define DD  2048
#define EE  64
#define MT  32           // tokens per block
#define BK  128          // k per chunk = 4 MFMA sub-steps of 32
#define NKC 8            // chunks per K-group (group covers 1024)
#define LDA 136          // halves per token row per split (272B stride, padded)
#define XREG (MT * LDA)  // halves per (g,buf,split) region
#define NBLK (TOK / MT)  // 512 gating blocks

typedef _Float16 half4v __attribute__((ext_vector_type(4)));
typedef _Float16 half8  __attribute__((ext_vector_type(8)));
typedef float    floatx4 __attribute__((ext_vector_type(4)));

// ---- W pre-split: f32 -> (hi,lo) f16, frag-major layout ----
// wf frag index ((ct*64+kc)*2+s)*64+lane, 8 halves each (kc = 32-k chunk 0..63).
// ct 0..3 = gate col-tiles (cols ct*16+cl), ct 4..7 = noise col-tiles.
// Also zeroes the aux workspace (cnt_g, psum_g, ticket) — stream order makes
// this visible to gating_kernel. 256 blocks x 128 thr = full-CU spread.
__global__ void build_wf(const float* __restrict__ Wg, const float* __restrict__ Wn,
                         _Float16* __restrict__ wf, float* __restrict__ zws) {
  if (blockIdx.x == 0) {
    if (threadIdx.x < 128) zws[threadIdx.x] = 0.f;
    if (threadIdx.x == 0)  ((int*)zws)[128] = 0;   // ticket
  }
  int tid  = blockIdx.x * 128 + threadIdx.x;   // 32768 threads
  int lane = tid & 63;
  int kc   = (tid >> 6) & 63;
  int ct   = tid >> 12;                        // 0..7
  int col  = (ct & 3) * 16 + (lane & 15);
  int k    = kc * 32 + (lane >> 4) * 8;
  const float* W = (ct < 4) ? Wg : Wn;
  const float* src = W + (size_t)col * DD + k;
  float4 a = *reinterpret_cast<const float4*>(src);
  float4 b = *reinterpret_cast<const float4*>(src + 4);
  float v[8] = {a.x, a.y, a.z, a.w, b.x, b.y, b.z, b.w};
  half8 hi, lo;
#pragma unroll
  for (int j = 0; j < 8; ++j) {
    _Float16 h = (_Float16)v[j];
    hi[j] = h;
    lo[j] = (_Float16)(v[j] - (float)h);
  }
  size_t base = (((size_t)(ct * 64 + kc) * 2 + 0) * 64 + lane) * 8;
  *reinterpret_cast<half8*>(wf + base)       = hi;
  *reinterpret_cast<half8*>(wf + base + 512) = lo;
}

// Convert+store one 128-float chunk row-slice (4x float4) into buffer BUF.
#define STAGE(BUF, P0, P1, P2, P3)                                              \
  {                                                                             \
    float4 pav[4] = {P0, P1, P2, P3};                                           \
    _Float16* xh = xs + ((g * 2 + (BUF)) * 2 + 0) * XREG + stok * LDA + skof;   \
    _Float16* xl = xh + XREG;                                                   \
    _Pragma("unroll")                                                           \
    for (int j = 0; j < 4; ++j) {                                               \
      float v[4] = {pav[j].x, pav[j].y, pav[j].z, pav[j].w};                    \
      half4v hi, lo;                                                            \
      _Pragma("unroll")                                                         \
      for (int jj = 0; jj < 4; ++jj) {                                          \
        _Float16 h = (_Float16)v[jj];                                           \
        hi[jj] = h;                                                             \
        lo[jj] = (_Float16)(v[jj] - (float)h);                                  \
      }                                                                         \
      *reinterpret_cast<half4v*>(xh + j * 32) = hi;                             \
      *reinterpret_cast<half4v*>(xl + j * 32) = lo;                             \
    }                                                                           \
  }

// One 32-k MFMA sub-step: consume B slot SC, prefetch next sub-step into SP.
// MFMA order (hi*hi, hi*lo, lo*hi) and k-order identical to the verified kernel.
#define SUBK(KK, SC, SP, DOPF)                                                  \
  {                                                                             \
    half8 Ah[2], Al[2];                                                         \
    _Pragma("unroll")                                                           \
    for (int mt = 0; mt < 2; ++mt) {                                            \
      Ah[mt] = *reinterpret_cast<const half8*>(xsh + (mt * 16) * LDA + (KK) * 32); \
      Al[mt] = *reinterpret_cast<const half8*>(xsl + (mt * 16) * LDA + (KK) * 32); \
    }                                                                           \
    if (DOPF) {                                                                 \
      const int ck = g * 32 + kc * 4 + (KK) + 1;                                \
      _Pragma("unroll")                                                         \
      for (int nt = 0; nt < 2; ++nt) {                                          \
        const int ct = w4 + nt * 4;                                             \
        _Pragma("unroll")                                                       \
        for (int s = 0; s < 2; ++s)                                             \
          SP[nt][s] = wfp[((size_t)(ct * 64 + ck) * 2 + s) * 64 + l];           \
      }                                                                         \
    }                                                                           \
    _Pragma("unroll")                                                           \
    for (int mt = 0; mt < 2; ++mt)                                              \
      _Pragma("unroll")                                                         \
      for (int nt = 0; nt < 2; ++nt)                                            \
        acc[mt][nt] = __builtin_amdgcn_mfma_f32_16x16x32_f16(Ah[mt], SC[nt][0], acc[mt][nt], 0, 0, 0); \
    _Pragma("unroll")                                                           \
    for (int mt = 0; mt < 2; ++mt)                                              \
      _Pragma("unroll")                                                         \
      for (int nt = 0; nt < 2; ++nt)                                            \
        acc[mt][nt] = __builtin_amdgcn_mfma_f32_16x16x32_f16(Ah[mt], SC[nt][1], acc[mt][nt], 0, 0, 0); \
    _Pragma("unroll")                                                           \
    for (int mt = 0; mt < 2; ++mt)                                              \
      _Pragma("unroll")                                                         \
      for (int nt = 0; nt < 2; ++nt)                                            \
        acc[mt][nt] = __builtin_amdgcn_mfma_f32_16x16x32_f16(Al[mt], SC[nt][0], acc[mt][nt], 0, 0, 0); \
  }

// LDS plan:
//   K-phase : xs[(g*2+buf)*2+split][32*LDA] halves = 8 regions x 8704 B = 69632 B
//   E-phase : overlay — Pacc 64x64 f32 @0 | Vb[32][66] @16384 | Eb[32][66] @24832
//             isum @33280 | ti @33408 | tp @33664  (33920 B < 69632)
__global__ __launch_bounds__(512, 4)
void gating_kernel(const float* __restrict__ x, const float* __restrict__ rn,
                   const _Float16* __restrict__ wf, const float* __restrict__ bg,
                   float* __restrict__ out,
                   float* __restrict__ cnt_g, float* __restrict__ psum_g,
                   int* __restrict__ ticket) {
  __shared__ char smem[69632];
  __shared__ int  lastflag;
  _Float16* xs   = (_Float16*)smem;
  float*    Pacc = (float*)smem;
  float*    Vb   = (float*)(smem + 16384);
  float*    Eb   = (float*)(smem + 24832);
  float*    isum = (float*)(smem + 33280);
  int*      ti   = (int*)(smem + 33408);
  float*    tp   = (float*)(smem + 33664);

  const int t  = threadIdx.x;
  const int g  = t >> 8;        // K-group: 0 -> K[0,1024), 1 -> K[1024,2048)
  const int tg = t & 255;
  const int w4 = tg >> 6;       // ct-pair 0..3 -> expert cols [w4*16, +16)
  const int l  = t & 63;
  const int q  = l >> 4;
  const int cl = l & 15;
  const int c  = w4 * 16 + cl;
  const int t0 = blockIdx.x * MT;

  // x staging (per group): thread covers token tg>>3, float-offset (tg&7)*4
  const int stok = tg >> 3;
  const int skof = (tg & 7) * 4;
  const float* xrow = x + (size_t)(t0 + stok) * DD + g * (NKC * BK) + skof;

  // epilogue operands (group 0 only)
  float bgv = 0.f;
  float rnv[2][4] = {{0.f,0.f,0.f,0.f},{0.f,0.f,0.f,0.f}};
  if (g == 0) {
    bgv = bg[c];
#pragma unroll
    for (int mt = 0; mt < 2; ++mt)
#pragma unroll
      for (int r = 0; r < 4; ++r)
        rnv[mt][r] = rn[(size_t)(t0 + mt * 16 + q * 4 + r) * EE + c];
  }

  floatx4 acc[2][2];
#pragma unroll
  for (int mt = 0; mt < 2; ++mt)
#pragma unroll
    for (int nt = 0; nt < 2; ++nt) acc[mt][nt] = (floatx4)0.f;

  const half8* wfp = (const half8*)wf;
  half8 Bs0[2][2], Bs1[2][2];   // static 2-slot ring, distance-1 prefetch

  // ---- preamble: stage chunk 0 of this group; load B sub-step 0 ----
  {
    float4 a0 = *reinterpret_cast<const float4*>(xrow);
    float4 a1 = *reinterpret_cast<const float4*>(xrow + 32);
    float4 a2 = *reinterpret_cast<const float4*>(xrow + 64);
    float4 a3 = *reinterpret_cast<const float4*>(xrow + 96);
    STAGE(0, a0, a1, a2, a3)
    const int ck0 = g * 32;
#pragma unroll
    for (int nt = 0; nt < 2; ++nt) {
      const int ct = w4 + nt * 4;
#pragma unroll
      for (int s = 0; s < 2; ++s)
        Bs0[nt][s] = wfp[((size_t)(ct * 64 + ck0) * 2 + s) * 64 + l];
    }
  }

#pragma unroll
  for (int kc = 0; kc < NKC; ++kc) {
    const int cur = kc & 1;
    const bool more = (kc < NKC - 1);
    float4 p0, p1, p2, p3;
    if (more) {
      const float* xn = xrow + (kc + 1) * BK;
      p0 = *reinterpret_cast<const float4*>(xn);
      p1 = *reinterpret_cast<const float4*>(xn + 32);
      p2 = *reinterpret_cast<const float4*>(xn + 64);
      p3 = *reinterpret_cast<const float4*>(xn + 96);
    }
    // counted barrier: order LDS producer->consumer, leave global loads in flight
    asm volatile("s_waitcnt lgkmcnt(0)" ::: "memory");
    __builtin_amdgcn_s_barrier();

    const _Float16* xsh = xs + ((g * 2 + cur) * 2 + 0) * XREG + cl * LDA + q * 8;
    const _Float16* xsl = xsh + XREG;

    SUBK(0, Bs0, Bs1, 1)
    SUBK(1, Bs1, Bs0, 1)
    SUBK(2, Bs0, Bs1, 1)
    SUBK(3, Bs1, Bs0, more)   // prefetches next chunk's sub-step 0 into Bs0

    if (more) {
      STAGE(cur ^ 1, p0, p1, p2, p3)
    }
  }

  __syncthreads();   // xs dead; smem becomes Pacc/Vb/Eb (full drain OK, once)

  // ---- split-K merge: group 1 -> LDS, group 0 adds ----
  if (g == 1) {
#pragma unroll
    for (int mt = 0; mt < 2; ++mt)
#pragma unroll
      for (int nt = 0; nt < 2; ++nt)
#pragma unroll
        for (int r = 0; r < 4; ++r)
          Pacc[((((w4 * 2 + mt) * 2 + nt) * 4) + r) * 64 + l] = acc[mt][nt][r];
  }
  __syncthreads();

  if (g == 0) {
#pragma unroll
    for (int mt = 0; mt < 2; ++mt)
#pragma unroll
      for (int nt = 0; nt < 2; ++nt)
#pragma unroll
        for (int r = 0; r < 4; ++r)
          acc[mt][nt][r] += Pacc[((((w4 * 2 + mt) * 2 + nt) * 4) + r) * 64 + l];

    // lane pass: noisy logit + exp, in-register (gate/noise same lane)
#pragma unroll
    for (int mt = 0; mt < 2; ++mt)
#pragma unroll
      for (int r = 0; r < 4; ++r) {
        const int tk = mt * 16 + q * 4 + r;   // C/D layout: row = q*4+r
        float gt = acc[mt][0][r] + bgv;
        float h  = acc[mt][1][r];
        float sp = (h > 20.f) ? h : log1pf(expf(h));
        float v  = gt + rnv[mt][r] * (sp + 0.01f);
        Vb[tk * 66 + c] = v;
        Eb[tk * 66 + c] = expf(v);
      }
  }
  __syncthreads();

  // ---- per-token top-2 + softmax denom (32 threads) ----
  if (t < MT) {
    float v1 = -1e30f, v2 = -1e30f;
    int   i1 = 0, i2 = 0;
    float s = 0.f;
    for (int e = 0; e < EE; ++e) {
      float v = Vb[t * 66 + e];
      s += Eb[t * 66 + e];
      if (v > v1)      { v2 = v1; i2 = i1; v1 = v; i1 = e; }
      else if (v > v2) { v2 = v;  i2 = e; }
    }
    isum[t] = 1.f / s;
    ti[t * 2 + 0] = i1; ti[t * 2 + 1] = i2;
    float e2 = expf(v2 - v1);
    float dn = 1.f + e2;
    tp[t * 2 + 0] = 1.f / dn;
    tp[t * 2 + 1] = e2 / dn;
  }
  __syncthreads();

  // ---- sparse out: patched zero-fill, all 512 threads, one float4 each ----
  {
    const int m  = t >> 4;
    const int c0 = (t & 15) * 4;
    const int i1 = ti[m * 2 + 0], i2 = ti[m * 2 + 1];
    const float p1 = tp[m * 2 + 0], p2 = tp[m * 2 + 1];
    float o[4];
#pragma unroll
    for (int j = 0; j < 4; ++j) {
      const int col = c0 + j;
      o[j] = (col == i1) ? p1 : ((col == i2) ? p2 : 0.f);
    }
    *reinterpret_cast<float4*>(out + (size_t)(t0 + m) * EE + c0) =
        make_float4(o[0], o[1], o[2], o[3]);
  }

  // ---- aux partials: per-expert psum & count ----
  if (t < EE) {
    float s = 0.f;
    int   cn = 0;
#pragma unroll
    for (int m = 0; m < MT; ++m) {
      s  += Eb[m * 66 + t] * isum[m];
      cn += (ti[m * 2 + 0] == t) + (ti[m * 2 + 1] == t);
    }
    atomicAdd(&psum_g[t], s);
    atomicAdd(&cnt_g[t], (float)cn);
  }

  // ---- fused aux finalization: last block reduces (replaces aux_kernel) ----
  __syncthreads();              // this block's atomicAdds issued
  if (t == 0) {
    __threadfence();            // order our adds before the ticket
    int old = atomicAdd(ticket, 1);
    lastflag = (old == NBLK - 1) ? 1 : 0;
  }
  __syncthreads();
  if (lastflag && t < EE) {
    __threadfence();            // acquire: all blocks' adds visible
    float v = ((volatile float*)cnt_g)[t] * ((volatile float*)psum_g)[t];
#pragma unroll
    for (int o = 32; o > 0; o >>= 1) v += __shfl_down(v, o);
    if (t == 0)
      out[(size_t)TOK * EE] = v * ((float)EE / ((float)TOK * (float)TOK));
  }
}

extern "C" void kernel_launch(void* const* d_in, const int* in_sizes, int n_in,
                              void* d_out, int out_size, void* d_ws, size_t ws_size,
                              hipStream_t stream) {
  const float* x  = (const float*)d_in[0];
  const float* rn = (const float*)d_in[1];
  const float* Wg = (const float*)d_in[2];
  const float* bg = (const float*)d_in[3];
  const float* Wn = (const float*)d_in[4];
  float* out    = (float*)d_out;
  float* cnt_g  = (float*)d_ws;                      // [0..63]
  float* psum_g = cnt_g + EE;                        // [64..127]
  int*   ticket = (int*)(cnt_g + 128);               // [128]
  _Float16* wf  = (_Float16*)((float*)d_ws + 256);   // 1 MiB of pre-split W frags

  build_wf<<<256, 128, 0, stream>>>(Wg, Wn, wf, cnt_g);
  gating_kernel<<<NBLK, 512, 0, stream>>>(x, rn, wf, bg, out, cnt_g, psum_g, ticket);
}